// Round 8
// baseline (609.812 us; speedup 1.0000x reference)
//
#include <hip/hip_runtime.h>
#include <stdint.h>

#define B_ROWS 4096
#define D_DIM  1024
#define E_NUM  8
#define C_DIM  4096
#define LOSS_COEF 0.01f
#define EPS_COMBINE 2.220446049250313e-16f

typedef float  f32x4  __attribute__((ext_vector_type(4)));
typedef __bf16 bf16x8 __attribute__((ext_vector_type(8)));

// RNE float -> bf16 bits (values here are tame; no NaN handling needed)
static __device__ __forceinline__ unsigned short f2bf(float f) {
    unsigned int u = __float_as_uint(f);
    u += 0x7fffu + ((u >> 16) & 1u);
    return (unsigned short)(u >> 16);
}

// async global->LDS, 16B per lane; LDS dest = wave-uniform base + lane*16
static __device__ __forceinline__ void async16(const void* g, void* l) {
    __builtin_amdgcn_global_load_lds(
        (const __attribute__((address_space(1))) unsigned int*)g,
        (__attribute__((address_space(3))) unsigned int*)l, 16, 0, 0);
}

#define TP_BLOCKS (8 * 8 * 32)   // 2048 transpose blocks (128x128 tiles)

// Fused prep (r7-proven): blocks [0, TP_BLOCKS) transpose w_exp fp32
// [8][1024][4096] -> wT bf16 [8][4096][1024] (128x128 tiles, XOR-swizzled
// LDS); blocks [TP_BLOCKS, +1024) do gating (logits, top-4 softmax, gates,
// stats atomics, xb emission). NOTE r5-vs-r7 A/B: transpose tile geometry
// (64² vs 128²) does NOT move the prep phase (~200us both) — granule-
// fragmentation theory falsified; prep bottleneck still undiagnosed.
__global__ __launch_bounds__(256) void prep_kernel(
    const float* __restrict__ x,
    const float* __restrict__ wg,
    const float* __restrict__ wexp,
    unsigned short* __restrict__ xb,
    unsigned short* __restrict__ wT,
    float* __restrict__ gates,
    float* __restrict__ stats)
{
    const int t = threadIdx.x;
    if ((int)blockIdx.x < TP_BLOCKS) {
        __shared__ unsigned short Tt[128 * 128];   // 32KB, swizzled [k][g']
        const int bid = blockIdx.x;
        const int ct = bid & 31;          // c-tile fastest: adjacent blocks
        const int kt = (bid >> 5) & 7;    //   read adjacent 512B chunks
        const int e  = bid >> 8;
        const int k0 = kt * 128, c0 = ct * 128;
        const float* src = wexp + ((size_t)e * D_DIM + k0) * C_DIM + c0;

        // phase 1: load 128 rows x 512B (fp32), convert, swizzled LDS store
        #pragma unroll
        for (int i = 0; i < 16; ++i) {
            const int kr = i * 8 + (t >> 5);          // row in tile
            const int g  = t & 31;                    // 4-col group
            float4 v = *(const float4*)(src + (size_t)kr * C_DIM + g * 4);
            unsigned short h[4] = { f2bf(v.x), f2bf(v.y), f2bf(v.z), f2bf(v.w) };
            const int gp = g ^ (((kr >> 4) & 7) << 1);
            *(uint2*)&Tt[kr * 128 + gp * 4] = *(const uint2*)h;
        }
        __syncthreads();

        // phase 2: per task (c, kch): gather 16 k's for column c, write 32B.
        // 8-lane groups share c with kch 0..7 -> 256B contiguous per c-row.
        unsigned short* dst = wT + (size_t)e * C_DIM * D_DIM
                            + (size_t)c0 * D_DIM + k0;
        #pragma unroll
        for (int i = 0; i < 4; ++i) {
            const int task = i * 256 + t;
            const int kch  = task & 7;
            const int c    = task >> 3;               // 0..127
            const int g    = c >> 2;
            unsigned short hh[16];
            #pragma unroll
            for (int j = 0; j < 16; ++j) {
                const int k  = kch * 16 + j;
                const int gp = g ^ (((k >> 4) & 7) << 1);
                hh[j] = Tt[k * 128 + gp * 4 + (c & 3)];
            }
            *(uint4*)(dst + (size_t)c * D_DIM + kch * 16)     = ((const uint4*)hh)[0];
            *(uint4*)(dst + (size_t)c * D_DIM + kch * 16 + 8) = ((const uint4*)hh)[1];
        }
    } else {
        __shared__ float simp[E_NUM], sload[E_NUM];
        if (t < E_NUM) { simp[t] = 0.0f; sload[t] = 0.0f; }
        __syncthreads();
        const int lane = t & 63;
        const int wid  = t >> 6;
        const int row  = ((int)blockIdx.x - TP_BLOCKS) * 4 + wid;

        float acc[8] = {0.f,0.f,0.f,0.f,0.f,0.f,0.f,0.f};
        #pragma unroll
        for (int i = 0; i < 4; ++i) {
            int d = i * 256 + lane * 4;
            float4 xv = *(const float4*)(x + (size_t)row * D_DIM + d);
            unsigned short hh[4] = { f2bf(xv.x), f2bf(xv.y), f2bf(xv.z), f2bf(xv.w) };
            *(uint2*)(xb + (size_t)row * D_DIM + d) = *(const uint2*)hh;
            float xa[4] = { xv.x, xv.y, xv.z, xv.w };
            #pragma unroll
            for (int j = 0; j < 4; ++j) {
                const float4* wp = (const float4*)(wg + (size_t)(d + j) * 8);
                float4 w0 = wp[0], w1 = wp[1];
                acc[0] += xa[j] * w0.x; acc[1] += xa[j] * w0.y;
                acc[2] += xa[j] * w0.z; acc[3] += xa[j] * w0.w;
                acc[4] += xa[j] * w1.x; acc[5] += xa[j] * w1.y;
                acc[6] += xa[j] * w1.z; acc[7] += xa[j] * w1.w;
            }
        }
        #pragma unroll
        for (int off = 32; off > 0; off >>= 1)
            #pragma unroll
            for (int e = 0; e < 8; ++e)
                acc[e] += __shfl_xor(acc[e], off, 64);
        if (lane == 0) {
            float val[4]; int idx[4]; unsigned used = 0;
            #pragma unroll
            for (int j = 0; j < 4; ++j) {       // strict > : lowest index wins ties
                float best = -1e30f; int bi = 0;
                for (int ee = 0; ee < 8; ++ee)
                    if (!(used & (1u << ee)) && acc[ee] > best) { best = acc[ee]; bi = ee; }
                used |= 1u << bi; val[j] = best; idx[j] = bi;
            }
            float mx = val[0], sum = 0.f, gv[4];
            #pragma unroll
            for (int j = 0; j < 4; ++j) { gv[j] = __expf(val[j] - mx); sum += gv[j]; }
            float inv = 1.0f / sum;
            float gout[8] = {0.f,0.f,0.f,0.f,0.f,0.f,0.f,0.f};
            #pragma unroll
            for (int j = 0; j < 4; ++j) gout[idx[j]] = gv[j] * inv;
            #pragma unroll
            for (int e = 0; e < 8; ++e) gates[(size_t)row * 8 + e] = gout[e];
            #pragma unroll
            for (int j = 0; j < 4; ++j) {
                atomicAdd(&simp[idx[j]], gv[j] * inv);
                atomicAdd(&sload[idx[j]], 1.0f);
            }
        }
        __syncthreads();
        if (t < E_NUM) {
            atomicAdd(&stats[t],          simp[t]);
            atomicAdd(&stats[E_NUM + t],  sload[t]);
        }
    }
}

__global__ void loss_kernel(const float* __restrict__ stats, float* __restrict__ out_loss) {
    if (threadIdx.x == 0) {
        float mi = 0.f, ml = 0.f;
        for (int e = 0; e < 8; ++e) { mi += stats[e]; ml += stats[8 + e]; }
        mi *= 0.125f; ml *= 0.125f;
        float vi = 0.f, vl = 0.f;
        for (int e = 0; e < 8; ++e) {
            float a = stats[e] - mi;     vi += a * a;
            float b = stats[8 + e] - ml; vl += b * b;
        }
        vi *= (1.0f / 7.0f); vl *= (1.0f / 7.0f);
        out_loss[0] = (vi / (mi * mi + 1e-10f) + vl / (ml * ml + 1e-10f)) * LOSS_COEF;
    }
}

// Fused dense MoE — FROZEN round-0 structure (353us, validated again r7).
// INSTRUMENTATION (this round): launched as 3 row-panel slices (11/11/10
// panels x 64 col panels = 704/704/640 blocks, >=2.5 blocks/CU preserved;
// per-block code identical, pbase arg only). Purpose: drop each dispatch
// to ~120us so prep_kernel (if >=125us) surfaces in rocprof top-5 with its
// own counter row — prep has been invisible behind 353us moe rows for 7
// rounds while costing ~200us/iter unexplained.
__global__ __launch_bounds__(256, 3) void moe_main_kernel(
    const unsigned short* __restrict__ xb,   // bf16 bits [4096][1024]
    const unsigned short* __restrict__ wT,   // bf16 bits [8][4096][1024]
    const float* __restrict__ bexp,          // [8][4096]
    const float* __restrict__ gates,         // [4096][8]
    float* __restrict__ out,                 // [4096][4096]
    int pbase)                               // row-panel base for this slice
{
    __shared__ unsigned short As[128 * 32];      // [m][k-chunk swizzled], 8KB
    __shared__ unsigned short Bs[2 * 64 * 32];   // [e][n][k-chunk swizzled], 8KB
    __shared__ float gs[128 * 9];                // gates tile (pad 9)
    __shared__ float bs[8 * 64];                 // bias tile

    const int tid  = threadIdx.x;
    const int lane = tid & 63;
    const int wid  = tid >> 6;     // 0..3
    const int wm   = wid >> 1;     // 2x2 wave grid: 64 rows x 32 cols each
    const int wn   = wid & 1;
    const int q    = lane >> 4;
    const int ln   = lane & 15;
    const int row0 = (pbase + blockIdx.x) * 128;
    const int col0 = blockIdx.y * 64;

    #pragma unroll
    for (int i = 0; i < 4; ++i) {
        int idx = i * 256 + tid;
        gs[(idx >> 3) * 9 + (idx & 7)] = gates[(size_t)row0 * 8 + idx];
    }
    {
        int e = tid >> 5, c = tid & 31;
        bs[e * 64 + c]      = bexp[(size_t)e * C_DIM + col0 + c];
        bs[e * 64 + c + 32] = bexp[(size_t)e * C_DIM + col0 + c + 32];
    }

    // staging: thread t -> LDS slot (row = t>>2, qs = t&3), source chunk
    // qg = qs ^ (row&3) (XOR swizzle); fragment reads use chunk q^(ln&3).
    const int rS = tid >> 2;                 // A row 0..63(+64) / B col 0..63
    const int qg = (tid & 3) ^ (rS & 3);
    const unsigned short* gA  = xb + (size_t)(row0 + rS) * D_DIM + qg * 8;
    const unsigned short* gBb = wT + (size_t)(col0 + rS) * D_DIM + qg * 8;
    char* ldsA = (char*)As + wid * 1024;     // wave-uniform base; HW adds lane*16
    char* ldsB = (char*)Bs + wid * 1024;

    const int fq = ((q ^ (ln & 3)) << 3);    // swizzled fragment chunk (shorts)

    const f32x4 vzero = {0.f, 0.f, 0.f, 0.f};
    f32x4 comb[4][2];
    #pragma unroll
    for (int i = 0; i < 4; ++i)
        #pragma unroll
        for (int j = 0; j < 2; ++j) comb[i][j] = vzero;

    for (int eg = 0; eg < 4; ++eg) {
        f32x4 acc[4][2][2];                  // [fm][fn][expert]
        #pragma unroll
        for (int i = 0; i < 4; ++i)
            #pragma unroll
            for (int j = 0; j < 2; ++j)
                #pragma unroll
                for (int e = 0; e < 2; ++e) acc[i][j][e] = vzero;

        const unsigned short* gB0 = gBb + (size_t)(2 * eg)     * C_DIM * D_DIM;
        const unsigned short* gB1 = gBb + (size_t)(2 * eg + 1) * C_DIM * D_DIM;

        for (int kt = 0; kt < D_DIM / 32; ++kt) {
            const int ko = kt * 32;
            async16(gA + ko,               ldsA);          // A rows 0-63
            async16(gA + ko + 64 * D_DIM,  ldsA + 4096);   // A rows 64-127
            async16(gB0 + ko,              ldsB);          // B expert 0
            async16(gB1 + ko,              ldsB + 4096);   // B expert 1

            __syncthreads();

            bf16x8 af[4], bfr[2][2];
            #pragma unroll
            for (int fm = 0; fm < 4; ++fm)
                af[fm] = *(const bf16x8*)(As + (wm * 64 + fm * 16 + ln) * 32 + fq);
            #pragma unroll
            for (int fn = 0; fn < 2; ++fn)
                #pragma unroll
                for (int e = 0; e < 2; ++e)
                    bfr[fn][e] = *(const bf16x8*)(Bs + e * 2048 +
                                    (wn * 32 + fn * 16 + ln) * 32 + fq);
            #pragma unroll
            for (int fm = 0; fm < 4; ++fm)
                #pragma unroll
                for (int fn = 0; fn < 2; ++fn)
                    #pragma unroll
                    for (int e = 0; e < 2; ++e)
                        acc[fm][fn][e] = __builtin_amdgcn_mfma_f32_16x16x32_bf16(
                            af[fm], bfr[fn][e], acc[fm][fn][e], 0, 0, 0);

            __syncthreads();
        }

        // epilogue: comb += gate * exp(acc + bias)   (C/D: col=ln, row=q*4+r)
        #pragma unroll
        for (int e = 0; e < 2; ++e) {
            int eG = eg * 2 + e;
            #pragma unroll
            for (int fn = 0; fn < 2; ++fn) {
                float bval = bs[eG * 64 + wn * 32 + fn * 16 + ln];
                #pragma unroll
                for (int fm = 0; fm < 4; ++fm)
                    #pragma unroll
                    for (int r = 0; r < 4; ++r) {
                        float g = gs[(wm * 64 + fm * 16 + q * 4 + r) * 9 + eG];
                        comb[fm][fn][r] += g * __expf(acc[fm][fn][e][r] + bval);
                    }
            }
        }
    }

    #pragma unroll
    for (int fm = 0; fm < 4; ++fm)
        #pragma unroll
        for (int fn = 0; fn < 2; ++fn)
            #pragma unroll
            for (int r = 0; r < 4; ++r) {
                int row = row0 + wm * 64 + fm * 16 + q * 4 + r;
                int col = col0 + wn * 32 + fn * 16 + ln;
                float c = comb[fm][fn][r];
                c = (c == 0.0f) ? EPS_COMBINE : c;
                out[(size_t)row * C_DIM + col] = __logf(c);
            }
}

extern "C" void kernel_launch(void* const* d_in, const int* in_sizes, int n_in,
                              void* d_out, int out_size, void* d_ws, size_t ws_size,
                              hipStream_t stream) {
    const float* x    = (const float*)d_in[0];
    const float* wg   = (const float*)d_in[1];
    const float* wexp = (const float*)d_in[2];
    const float* bexp = (const float*)d_in[3];
    // d_in[4] is k==4 (hard-coded in kernels)
    float* out = (float*)d_out;
    char*  ws  = (char*)d_ws;

    unsigned short* wT    = (unsigned short*)ws;               // 67108864 B
    unsigned short* xb    = (unsigned short*)(ws + 67108864);  // 8388608 B
    float*          gates = (float*)(ws + 75497472);           // 131072 B
    float*          stats = (float*)(ws + 75628544);           // 64 B

    hipMemsetAsync(stats, 0, 16 * sizeof(float), stream);
    prep_kernel<<<TP_BLOCKS + B_ROWS / 4, 256, 0, stream>>>(
        x, wg, wexp, xb, wT, gates, stats);
    loss_kernel<<<1, 64, 0, stream>>>(stats, out + (size_t)B_ROWS * C_DIM);

    // moe in 3 row-panel slices (11/11/10 of 32) — instrumentation split so
    // prep_kernel can surface in rocprof top-5; >=2.5 blocks/CU kept.
    moe_main_kernel<<<dim3(11, C_DIM / 64), 256, 0, stream>>>(xb, wT, bexp, gates, out, 0);
    moe_main_kernel<<<dim3(11, C_DIM / 64), 256, 0, stream>>>(xb, wT, bexp, gates, out, 11);
    moe_main_kernel<<<dim3(10, C_DIM / 64), 256, 0, stream>>>(xb, wT, bexp, gates, out, 22);
}

// Round 9
// 564.770 us; speedup vs baseline: 1.0798x; 1.0798x over previous
//
#include <hip/hip_runtime.h>
#include <stdint.h>

#define B_ROWS 4096
#define D_DIM  1024
#define E_NUM  8
#define C_DIM  4096
#define LOSS_COEF 0.01f
#define EPS_COMBINE 2.220446049250313e-16f

typedef float  f32x4  __attribute__((ext_vector_type(4)));
typedef __bf16 bf16x8 __attribute__((ext_vector_type(8)));

// RNE float -> bf16 bits (values here are tame; no NaN handling needed)
static __device__ __forceinline__ unsigned short f2bf(float f) {
    unsigned int u = __float_as_uint(f);
    u += 0x7fffu + ((u >> 16) & 1u);
    return (unsigned short)(u >> 16);
}

// async global->LDS, 16B per lane; LDS dest = wave-uniform base + lane*16
static __device__ __forceinline__ void async16(const void* g, void* l) {
    __builtin_amdgcn_global_load_lds(
        (const __attribute__((address_space(1))) unsigned int*)g,
        (__attribute__((address_space(3))) unsigned int*)l, 16, 0, 0);
}

#define TP_BLOCKS 2048   // transpose tiles: 8 e x 4 k-tiles(256) x 64 c-tiles(64)

// Fused prep: blocks [0, TP_BLOCKS) transpose w_exp fp32 [8][1024][4096] ->
// wT bf16 [8][4096][1024] (k-contiguous). NEW: asymmetric [256 k][64 c]
// tile — write granule 512B contiguous (was 256B), read granule 256B.
// r5-vs-r7 falsified symmetric granule scaling; r8 showed read-dominant
// traffic sustains 2.77 TB/s while prep runs 1.5 — this probes the WRITE
// stream as the throttle. LDS 32KB, XOR swizzle c' = c ^ ((k>>3 & 15)<<2)
// (round-trip consistent: bits 0-1 of c untouched, k>>3 identical on both
// sides; ~2-way banks both phases).
// Blocks [TP_BLOCKS, +1024): gating WITHOUT stats atomics (loss_kernel now
// derives stats from gates) — saves the memset launch.
__global__ __launch_bounds__(256) void prep_kernel(
    const float* __restrict__ x,
    const float* __restrict__ wg,
    const float* __restrict__ wexp,
    unsigned short* __restrict__ xb,
    unsigned short* __restrict__ wT,
    float* __restrict__ gates)
{
    const int t = threadIdx.x;
    if ((int)blockIdx.x < TP_BLOCKS) {
        __shared__ unsigned short Tt[256 * 64];    // 32KB, swizzled [k][c']
        const int bid = blockIdx.x;
        const int ct = bid & 63;          // c-tile fastest: adjacent blocks
        const int kt = (bid >> 6) & 3;    //   read adjacent 256B chunks
        const int e  = bid >> 8;
        const int k0 = kt * 256, c0 = ct * 64;
        const float* src = wexp + ((size_t)e * D_DIM + k0) * C_DIM + c0;

        // phase 1: 256 rows x 256B fp32, convert, swizzled LDS store (8B)
        #pragma unroll
        for (int i = 0; i < 16; ++i) {
            const int kr = i * 16 + (t >> 4);         // row in tile
            const int cg = (t & 15) * 4;              // 4-col group
            float4 v = *(const float4*)(src + (size_t)kr * C_DIM + cg);
            unsigned short h[4] = { f2bf(v.x), f2bf(v.y), f2bf(v.z), f2bf(v.w) };
            const int cswz = cg ^ (((kr >> 3) & 15) << 2);
            *(uint2*)&Tt[kr * 64 + cswz] = *(const uint2*)h;
        }
        __syncthreads();

        // phase 2: task (c, ko8): gather 8 consecutive k's for col c, write
        // 16B. A wave covers 2 c's x full 512B k-range each -> 512B-contig
        // write granules at 2KB stride.
        unsigned short* dstb = wT + (size_t)e * C_DIM * D_DIM + k0;
        #pragma unroll
        for (int i = 0; i < 8; ++i) {
            const int task = i * 256 + t;
            const int ko8  = task & 31;               // 8-k chunk (0..31)
            const int c    = task >> 5;               // 0..63
            const int cswz = c ^ ((ko8 & 15) << 2);   // k>>3 == ko8 for j<8
            unsigned short hh[8];
            #pragma unroll
            for (int j = 0; j < 8; ++j)
                hh[j] = Tt[(ko8 * 8 + j) * 64 + cswz];
            *(uint4*)(dstb + (size_t)(c0 + c) * D_DIM + ko8 * 8) = *(const uint4*)hh;
        }
    } else {
        const int lane = t & 63;
        const int wid  = t >> 6;
        const int row  = ((int)blockIdx.x - TP_BLOCKS) * 4 + wid;

        float acc[8] = {0.f,0.f,0.f,0.f,0.f,0.f,0.f,0.f};
        #pragma unroll
        for (int i = 0; i < 4; ++i) {
            int d = i * 256 + lane * 4;
            float4 xv = *(const float4*)(x + (size_t)row * D_DIM + d);
            unsigned short hh[4] = { f2bf(xv.x), f2bf(xv.y), f2bf(xv.z), f2bf(xv.w) };
            *(uint2*)(xb + (size_t)row * D_DIM + d) = *(const uint2*)hh;
            float xa[4] = { xv.x, xv.y, xv.z, xv.w };
            #pragma unroll
            for (int j = 0; j < 4; ++j) {
                const float4* wp = (const float4*)(wg + (size_t)(d + j) * 8);
                float4 w0 = wp[0], w1 = wp[1];
                acc[0] += xa[j] * w0.x; acc[1] += xa[j] * w0.y;
                acc[2] += xa[j] * w0.z; acc[3] += xa[j] * w0.w;
                acc[4] += xa[j] * w1.x; acc[5] += xa[j] * w1.y;
                acc[6] += xa[j] * w1.z; acc[7] += xa[j] * w1.w;
            }
        }
        #pragma unroll
        for (int off = 32; off > 0; off >>= 1)
            #pragma unroll
            for (int e = 0; e < 8; ++e)
                acc[e] += __shfl_xor(acc[e], off, 64);
        if (lane == 0) {
            float val[4]; int idx[4]; unsigned used = 0;
            #pragma unroll
            for (int j = 0; j < 4; ++j) {       // strict > : lowest index wins ties
                float best = -1e30f; int bi = 0;
                for (int ee = 0; ee < 8; ++ee)
                    if (!(used & (1u << ee)) && acc[ee] > best) { best = acc[ee]; bi = ee; }
                used |= 1u << bi; val[j] = best; idx[j] = bi;
            }
            float mx = val[0], sum = 0.f, gv[4];
            #pragma unroll
            for (int j = 0; j < 4; ++j) { gv[j] = __expf(val[j] - mx); sum += gv[j]; }
            float inv = 1.0f / sum;
            float gout[8] = {0.f,0.f,0.f,0.f,0.f,0.f,0.f,0.f};
            #pragma unroll
            for (int j = 0; j < 4; ++j) gout[idx[j]] = gv[j] * inv;
            #pragma unroll
            for (int e = 0; e < 8; ++e) gates[(size_t)row * 8 + e] = gout[e];
        }
    }
}

// Stats + loss derived directly from gates[4096][8] (1 block, L2-resident
// 128KB read) — replaces the memset launch and gating-side atomics.
__global__ __launch_bounds__(256) void loss_kernel(
    const float* __restrict__ gates, float* __restrict__ out_loss) {
    __shared__ float sI[4][8], sC[4][8];
    const int t = threadIdx.x, lane = t & 63, wid = t >> 6;
    float imp[8] = {0,0,0,0,0,0,0,0}, cnt[8] = {0,0,0,0,0,0,0,0};
    for (int r = t; r < B_ROWS; r += 256) {
        const float4* gp = (const float4*)(gates + (size_t)r * 8);
        float4 g0 = gp[0], g1 = gp[1];
        imp[0] += g0.x; imp[1] += g0.y; imp[2] += g0.z; imp[3] += g0.w;
        imp[4] += g1.x; imp[5] += g1.y; imp[6] += g1.z; imp[7] += g1.w;
        cnt[0] += (g0.x > 0.f); cnt[1] += (g0.y > 0.f);
        cnt[2] += (g0.z > 0.f); cnt[3] += (g0.w > 0.f);
        cnt[4] += (g1.x > 0.f); cnt[5] += (g1.y > 0.f);
        cnt[6] += (g1.z > 0.f); cnt[7] += (g1.w > 0.f);
    }
    #pragma unroll
    for (int off = 32; off > 0; off >>= 1)
        #pragma unroll
        for (int e = 0; e < 8; ++e) {
            imp[e] += __shfl_xor(imp[e], off, 64);
            cnt[e] += __shfl_xor(cnt[e], off, 64);
        }
    if (lane == 0)
        #pragma unroll
        for (int e = 0; e < 8; ++e) { sI[wid][e] = imp[e]; sC[wid][e] = cnt[e]; }
    __syncthreads();
    if (t == 0) {
        float I[8], C[8];
        for (int e = 0; e < 8; ++e) {
            I[e] = sI[0][e] + sI[1][e] + sI[2][e] + sI[3][e];
            C[e] = sC[0][e] + sC[1][e] + sC[2][e] + sC[3][e];
        }
        float mi = 0.f, ml = 0.f;
        for (int e = 0; e < 8; ++e) { mi += I[e]; ml += C[e]; }
        mi *= 0.125f; ml *= 0.125f;
        float vi = 0.f, vl = 0.f;
        for (int e = 0; e < 8; ++e) {
            float a = I[e] - mi; vi += a * a;
            float b = C[e] - ml; vl += b * b;
        }
        vi *= (1.0f / 7.0f); vl *= (1.0f / 7.0f);
        out_loss[0] = (vi / (mi * mi + 1e-10f) + vl / (ml * ml + 1e-10f)) * LOSS_COEF;
    }
}

// Fused dense MoE — FROZEN round-0 structure (354us, re-validated r7/r8).
// Tile 128 rows x 64 cols, 4 waves (2x2), each wave 64x32 x 2 experts per
// pass (4 passes). XOR-swizzled quad-contiguous gather + fq-compensated
// fragment reads; bias/gates in LDS (register budget saturated: +16
// always-live VGPR crosses the (256,3) spill cliff — r2/r3).
__global__ __launch_bounds__(256, 3) void moe_main_kernel(
    const unsigned short* __restrict__ xb,   // bf16 bits [4096][1024]
    const unsigned short* __restrict__ wT,   // bf16 bits [8][4096][1024]
    const float* __restrict__ bexp,          // [8][4096]
    const float* __restrict__ gates,         // [4096][8]
    float* __restrict__ out)                 // [4096][4096]
{
    __shared__ unsigned short As[128 * 32];      // [m][k-chunk swizzled], 8KB
    __shared__ unsigned short Bs[2 * 64 * 32];   // [e][n][k-chunk swizzled], 8KB
    __shared__ float gs[128 * 9];                // gates tile (pad 9)
    __shared__ float bs[8 * 64];                 // bias tile

    const int tid  = threadIdx.x;
    const int lane = tid & 63;
    const int wid  = tid >> 6;     // 0..3
    const int wm   = wid >> 1;     // 2x2 wave grid: 64 rows x 32 cols each
    const int wn   = wid & 1;
    const int q    = lane >> 4;
    const int ln   = lane & 15;
    const int row0 = blockIdx.x * 128;
    const int col0 = blockIdx.y * 64;

    #pragma unroll
    for (int i = 0; i < 4; ++i) {
        int idx = i * 256 + tid;
        gs[(idx >> 3) * 9 + (idx & 7)] = gates[(size_t)row0 * 8 + idx];
    }
    {
        int e = tid >> 5, c = tid & 31;
        bs[e * 64 + c]      = bexp[(size_t)e * C_DIM + col0 + c];
        bs[e * 64 + c + 32] = bexp[(size_t)e * C_DIM + col0 + c + 32];
    }

    // staging: thread t -> LDS slot (row = t>>2, qs = t&3), source chunk
    // qg = qs ^ (row&3) (XOR swizzle); fragment reads use chunk q^(ln&3).
    const int rS = tid >> 2;                 // A row 0..63(+64) / B col 0..63
    const int qg = (tid & 3) ^ (rS & 3);
    const unsigned short* gA  = xb + (size_t)(row0 + rS) * D_DIM + qg * 8;
    const unsigned short* gBb = wT + (size_t)(col0 + rS) * D_DIM + qg * 8;
    char* ldsA = (char*)As + wid * 1024;     // wave-uniform base; HW adds lane*16
    char* ldsB = (char*)Bs + wid * 1024;

    const int fq = ((q ^ (ln & 3)) << 3);    // swizzled fragment chunk (shorts)

    const f32x4 vzero = {0.f, 0.f, 0.f, 0.f};
    f32x4 comb[4][2];
    #pragma unroll
    for (int i = 0; i < 4; ++i)
        #pragma unroll
        for (int j = 0; j < 2; ++j) comb[i][j] = vzero;

    for (int eg = 0; eg < 4; ++eg) {
        f32x4 acc[4][2][2];                  // [fm][fn][expert]
        #pragma unroll
        for (int i = 0; i < 4; ++i)
            #pragma unroll
            for (int j = 0; j < 2; ++j)
                #pragma unroll
                for (int e = 0; e < 2; ++e) acc[i][j][e] = vzero;

        const unsigned short* gB0 = gBb + (size_t)(2 * eg)     * C_DIM * D_DIM;
        const unsigned short* gB1 = gBb + (size_t)(2 * eg + 1) * C_DIM * D_DIM;

        for (int kt = 0; kt < D_DIM / 32; ++kt) {
            const int ko = kt * 32;
            async16(gA + ko,               ldsA);          // A rows 0-63
            async16(gA + ko + 64 * D_DIM,  ldsA + 4096);   // A rows 64-127
            async16(gB0 + ko,              ldsB);          // B expert 0
            async16(gB1 + ko,              ldsB + 4096);   // B expert 1

            __syncthreads();

            bf16x8 af[4], bfr[2][2];
            #pragma unroll
            for (int fm = 0; fm < 4; ++fm)
                af[fm] = *(const bf16x8*)(As + (wm * 64 + fm * 16 + ln) * 32 + fq);
            #pragma unroll
            for (int fn = 0; fn < 2; ++fn)
                #pragma unroll
                for (int e = 0; e < 2; ++e)
                    bfr[fn][e] = *(const bf16x8*)(Bs + e * 2048 +
                                    (wn * 32 + fn * 16 + ln) * 32 + fq);
            #pragma unroll
            for (int fm = 0; fm < 4; ++fm)
                #pragma unroll
                for (int fn = 0; fn < 2; ++fn)
                    #pragma unroll
                    for (int e = 0; e < 2; ++e)
                        acc[fm][fn][e] = __builtin_amdgcn_mfma_f32_16x16x32_bf16(
                            af[fm], bfr[fn][e], acc[fm][fn][e], 0, 0, 0);

            __syncthreads();
        }

        // epilogue: comb += gate * exp(acc + bias)   (C/D: col=ln, row=q*4+r)
        #pragma unroll
        for (int e = 0; e < 2; ++e) {
            int eG = eg * 2 + e;
            #pragma unroll
            for (int fn = 0; fn < 2; ++fn) {
                float bval = bs[eG * 64 + wn * 32 + fn * 16 + ln];
                #pragma unroll
                for (int fm = 0; fm < 4; ++fm)
                    #pragma unroll
                    for (int r = 0; r < 4; ++r) {
                        float g = gs[(wm * 64 + fm * 16 + q * 4 + r) * 9 + eG];
                        comb[fm][fn][r] += g * __expf(acc[fm][fn][e][r] + bval);
                    }
            }
        }
    }

    #pragma unroll
    for (int fm = 0; fm < 4; ++fm)
        #pragma unroll
        for (int fn = 0; fn < 2; ++fn)
            #pragma unroll
            for (int r = 0; r < 4; ++r) {
                int row = row0 + wm * 64 + fm * 16 + q * 4 + r;
                int col = col0 + wn * 32 + fn * 16 + ln;
                float c = comb[fm][fn][r];
                c = (c == 0.0f) ? EPS_COMBINE : c;
                out[(size_t)row * C_DIM + col] = __logf(c);
            }
}

extern "C" void kernel_launch(void* const* d_in, const int* in_sizes, int n_in,
                              void* d_out, int out_size, void* d_ws, size_t ws_size,
                              hipStream_t stream) {
    const float* x    = (const float*)d_in[0];
    const float* wg   = (const float*)d_in[1];
    const float* wexp = (const float*)d_in[2];
    const float* bexp = (const float*)d_in[3];
    // d_in[4] is k==4 (hard-coded in kernels)
    float* out = (float*)d_out;
    char*  ws  = (char*)d_ws;

    unsigned short* wT    = (unsigned short*)ws;               // 67108864 B
    unsigned short* xb    = (unsigned short*)(ws + 67108864);  // 8388608 B
    float*          gates = (float*)(ws + 75497472);           // 131072 B

    // 3 launches: prep -> moe -> loss (no memset; loss derives stats from
    // gates; no 1-block kernel drains the GPU between prep and moe).
    prep_kernel<<<TP_BLOCKS + B_ROWS / 4, 256, 0, stream>>>(
        x, wg, wexp, xb, wT, gates);

    dim3 grid(B_ROWS / 128, C_DIM / 64);
    moe_main_kernel<<<grid, 256, 0, stream>>>(xb, wT, bexp, gates, out);

    loss_kernel<<<1, 256, 0, stream>>>(gates, out + (size_t)B_ROWS * C_DIM);
}

// Round 10
// 557.612 us; speedup vs baseline: 1.0936x; 1.0128x over previous
//
#include <hip/hip_runtime.h>
#include <stdint.h>

#define B_ROWS 4096
#define D_DIM  1024
#define E_NUM  8
#define C_DIM  4096
#define LOSS_COEF 0.01f
#define EPS_COMBINE 2.220446049250313e-16f

typedef float  f32x4  __attribute__((ext_vector_type(4)));
typedef __bf16 bf16x8 __attribute__((ext_vector_type(8)));

// RNE float -> bf16 bits (values here are tame; no NaN handling needed)
static __device__ __forceinline__ unsigned short f2bf(float f) {
    unsigned int u = __float_as_uint(f);
    u += 0x7fffu + ((u >> 16) & 1u);
    return (unsigned short)(u >> 16);
}

// async global->LDS, 16B per lane; LDS dest = wave-uniform base + lane*16
static __device__ __forceinline__ void async16(const void* g, void* l) {
    __builtin_amdgcn_global_load_lds(
        (const __attribute__((address_space(1))) unsigned int*)g,
        (__attribute__((address_space(3))) unsigned int*)l, 16, 0, 0);
}

#define TP_BLOCKS 2048   // transpose tiles: 8 e x 4 k-tiles(256) x 64 c-tiles(64)

// Fused prep (r9 version, FROZEN this round): blocks [0, TP_BLOCKS)
// transpose w_exp fp32 [8][1024][4096] -> wT bf16 [8][4096][1024]
// ([256 k][64 c] tiles); blocks [TP_BLOCKS, +1024) gating without atomics.
// Aux-phase ledger: ~205us constant across 64², 128², 256x64 tiles,
// +-atomics, 3-5 launches — every access-pattern theory falsified.
// prep < 131us (r8 bound); split between prep-exec and launch gaps UNKNOWN.
__global__ __launch_bounds__(256) void prep_kernel(
    const float* __restrict__ x,
    const float* __restrict__ wg,
    const float* __restrict__ wexp,
    unsigned short* __restrict__ xb,
    unsigned short* __restrict__ wT,
    float* __restrict__ gates)
{
    const int t = threadIdx.x;
    if ((int)blockIdx.x < TP_BLOCKS) {
        __shared__ unsigned short Tt[256 * 64];    // 32KB, swizzled [k][c']
        const int bid = blockIdx.x;
        const int ct = bid & 63;          // c-tile fastest: adjacent blocks
        const int kt = (bid >> 6) & 3;    //   read adjacent 256B chunks
        const int e  = bid >> 8;
        const int k0 = kt * 256, c0 = ct * 64;
        const float* src = wexp + ((size_t)e * D_DIM + k0) * C_DIM + c0;

        // phase 1: 256 rows x 256B fp32, convert, swizzled LDS store (8B)
        #pragma unroll
        for (int i = 0; i < 16; ++i) {
            const int kr = i * 16 + (t >> 4);         // row in tile
            const int cg = (t & 15) * 4;              // 4-col group
            float4 v = *(const float4*)(src + (size_t)kr * C_DIM + cg);
            unsigned short h[4] = { f2bf(v.x), f2bf(v.y), f2bf(v.z), f2bf(v.w) };
            const int cswz = cg ^ (((kr >> 3) & 15) << 2);
            *(uint2*)&Tt[kr * 64 + cswz] = *(const uint2*)h;
        }
        __syncthreads();

        // phase 2: task (c, ko8): gather 8 consecutive k's for col c, write
        // 16B. A wave covers 2 c's x full 512B k-range each -> 512B-contig
        // write granules at 2KB stride.
        unsigned short* dstb = wT + (size_t)e * C_DIM * D_DIM + k0;
        #pragma unroll
        for (int i = 0; i < 8; ++i) {
            const int task = i * 256 + t;
            const int ko8  = task & 31;               // 8-k chunk (0..31)
            const int c    = task >> 5;               // 0..63
            const int cswz = c ^ ((ko8 & 15) << 2);   // k>>3 == ko8 for j<8
            unsigned short hh[8];
            #pragma unroll
            for (int j = 0; j < 8; ++j)
                hh[j] = Tt[(ko8 * 8 + j) * 64 + cswz];
            *(uint4*)(dstb + (size_t)(c0 + c) * D_DIM + ko8 * 8) = *(const uint4*)hh;
        }
    } else {
        const int lane = t & 63;
        const int wid  = t >> 6;
        const int row  = ((int)blockIdx.x - TP_BLOCKS) * 4 + wid;

        float acc[8] = {0.f,0.f,0.f,0.f,0.f,0.f,0.f,0.f};
        #pragma unroll
        for (int i = 0; i < 4; ++i) {
            int d = i * 256 + lane * 4;
            float4 xv = *(const float4*)(x + (size_t)row * D_DIM + d);
            unsigned short hh[4] = { f2bf(xv.x), f2bf(xv.y), f2bf(xv.z), f2bf(xv.w) };
            *(uint2*)(xb + (size_t)row * D_DIM + d) = *(const uint2*)hh;
            float xa[4] = { xv.x, xv.y, xv.z, xv.w };
            #pragma unroll
            for (int j = 0; j < 4; ++j) {
                const float4* wp = (const float4*)(wg + (size_t)(d + j) * 8);
                float4 w0 = wp[0], w1 = wp[1];
                acc[0] += xa[j] * w0.x; acc[1] += xa[j] * w0.y;
                acc[2] += xa[j] * w0.z; acc[3] += xa[j] * w0.w;
                acc[4] += xa[j] * w1.x; acc[5] += xa[j] * w1.y;
                acc[6] += xa[j] * w1.z; acc[7] += xa[j] * w1.w;
            }
        }
        #pragma unroll
        for (int off = 32; off > 0; off >>= 1)
            #pragma unroll
            for (int e = 0; e < 8; ++e)
                acc[e] += __shfl_xor(acc[e], off, 64);
        if (lane == 0) {
            float val[4]; int idx[4]; unsigned used = 0;
            #pragma unroll
            for (int j = 0; j < 4; ++j) {       // strict > : lowest index wins ties
                float best = -1e30f; int bi = 0;
                for (int ee = 0; ee < 8; ++ee)
                    if (!(used & (1u << ee)) && acc[ee] > best) { best = acc[ee]; bi = ee; }
                used |= 1u << bi; val[j] = best; idx[j] = bi;
            }
            float mx = val[0], sum = 0.f, gv[4];
            #pragma unroll
            for (int j = 0; j < 4; ++j) { gv[j] = __expf(val[j] - mx); sum += gv[j]; }
            float inv = 1.0f / sum;
            float gout[8] = {0.f,0.f,0.f,0.f,0.f,0.f,0.f,0.f};
            #pragma unroll
            for (int j = 0; j < 4; ++j) gout[idx[j]] = gv[j] * inv;
            #pragma unroll
            for (int e = 0; e < 8; ++e) gates[(size_t)row * 8 + e] = gout[e];
        }
    }
}

// Stats + loss derived directly from gates[4096][8] (1 block, L2-resident
// 128KB read).
__global__ __launch_bounds__(256) void loss_kernel(
    const float* __restrict__ gates, float* __restrict__ out_loss) {
    __shared__ float sI[4][8], sC[4][8];
    const int t = threadIdx.x, lane = t & 63, wid = t >> 6;
    float imp[8] = {0,0,0,0,0,0,0,0}, cnt[8] = {0,0,0,0,0,0,0,0};
    for (int r = t; r < B_ROWS; r += 256) {
        const float4* gp = (const float4*)(gates + (size_t)r * 8);
        float4 g0 = gp[0], g1 = gp[1];
        imp[0] += g0.x; imp[1] += g0.y; imp[2] += g0.z; imp[3] += g0.w;
        imp[4] += g1.x; imp[5] += g1.y; imp[6] += g1.z; imp[7] += g1.w;
        cnt[0] += (g0.x > 0.f); cnt[1] += (g0.y > 0.f);
        cnt[2] += (g0.z > 0.f); cnt[3] += (g0.w > 0.f);
        cnt[4] += (g1.x > 0.f); cnt[5] += (g1.y > 0.f);
        cnt[6] += (g1.z > 0.f); cnt[7] += (g1.w > 0.f);
    }
    #pragma unroll
    for (int off = 32; off > 0; off >>= 1)
        #pragma unroll
        for (int e = 0; e < 8; ++e) {
            imp[e] += __shfl_xor(imp[e], off, 64);
            cnt[e] += __shfl_xor(cnt[e], off, 64);
        }
    if (lane == 0)
        #pragma unroll
        for (int e = 0; e < 8; ++e) { sI[wid][e] = imp[e]; sC[wid][e] = cnt[e]; }
    __syncthreads();
    if (t == 0) {
        float I[8], C[8];
        for (int e = 0; e < 8; ++e) {
            I[e] = sI[0][e] + sI[1][e] + sI[2][e] + sI[3][e];
            C[e] = sC[0][e] + sC[1][e] + sC[2][e] + sC[3][e];
        }
        float mi = 0.f, ml = 0.f;
        for (int e = 0; e < 8; ++e) { mi += I[e]; ml += C[e]; }
        mi *= 0.125f; ml *= 0.125f;
        float vi = 0.f, vl = 0.f;
        for (int e = 0; e < 8; ++e) {
            float a = I[e] - mi; vi += a * a;
            float b = C[e] - ml; vl += b * b;
        }
        vi *= (1.0f / 7.0f); vl *= (1.0f / 7.0f);
        out_loss[0] = (vi / (mi * mi + 1e-10f) + vl / (ml * ml + 1e-10f)) * LOSS_COEF;
    }
}

// Fused dense MoE — FROZEN round-0 structure (354us, re-validated r7/r8/r9).
// INSTRUMENTATION (this round): COLUMN-split into 3 slices (22/21/21 of 64
// col-panels x 32 row-panels). Unlike r8's row-split, col-split PARTITIONS
// wT (each slice reads its own cols exactly once; only 8MB xb re-read,
// L2/L3-resident) -> expect NO FETCH inflation, ~+10us total. Purpose:
// drop the top-5 visibility threshold to ~118us so prep (if in (118,131])
// surfaces with its own counter row; absence proves prep < 118 and
// launch-gap >= 85us -> fusion is next.
__global__ __launch_bounds__(256, 3) void moe_main_kernel(
    const unsigned short* __restrict__ xb,   // bf16 bits [4096][1024]
    const unsigned short* __restrict__ wT,   // bf16 bits [8][4096][1024]
    const float* __restrict__ bexp,          // [8][4096]
    const float* __restrict__ gates,         // [4096][8]
    float* __restrict__ out,                 // [4096][4096]
    int cbase)                               // col-panel base for this slice
{
    __shared__ unsigned short As[128 * 32];      // [m][k-chunk swizzled], 8KB
    __shared__ unsigned short Bs[2 * 64 * 32];   // [e][n][k-chunk swizzled], 8KB
    __shared__ float gs[128 * 9];                // gates tile (pad 9)
    __shared__ float bs[8 * 64];                 // bias tile

    const int tid  = threadIdx.x;
    const int lane = tid & 63;
    const int wid  = tid >> 6;     // 0..3
    const int wm   = wid >> 1;     // 2x2 wave grid: 64 rows x 32 cols each
    const int wn   = wid & 1;
    const int q    = lane >> 4;
    const int ln   = lane & 15;
    const int row0 = blockIdx.x * 128;
    const int col0 = (cbase + blockIdx.y) * 64;

    #pragma unroll
    for (int i = 0; i < 4; ++i) {
        int idx = i * 256 + tid;
        gs[(idx >> 3) * 9 + (idx & 7)] = gates[(size_t)row0 * 8 + idx];
    }
    {
        int e = tid >> 5, c = tid & 31;
        bs[e * 64 + c]      = bexp[(size_t)e * C_DIM + col0 + c];
        bs[e * 64 + c + 32] = bexp[(size_t)e * C_DIM + col0 + c + 32];
    }

    // staging: thread t -> LDS slot (row = t>>2, qs = t&3), source chunk
    // qg = qs ^ (row&3) (XOR swizzle); fragment reads use chunk q^(ln&3).
    const int rS = tid >> 2;                 // A row 0..63(+64) / B col 0..63
    const int qg = (tid & 3) ^ (rS & 3);
    const unsigned short* gA  = xb + (size_t)(row0 + rS) * D_DIM + qg * 8;
    const unsigned short* gBb = wT + (size_t)(col0 + rS) * D_DIM + qg * 8;
    char* ldsA = (char*)As + wid * 1024;     // wave-uniform base; HW adds lane*16
    char* ldsB = (char*)Bs + wid * 1024;

    const int fq = ((q ^ (ln & 3)) << 3);    // swizzled fragment chunk (shorts)

    const f32x4 vzero = {0.f, 0.f, 0.f, 0.f};
    f32x4 comb[4][2];
    #pragma unroll
    for (int i = 0; i < 4; ++i)
        #pragma unroll
        for (int j = 0; j < 2; ++j) comb[i][j] = vzero;

    for (int eg = 0; eg < 4; ++eg) {
        f32x4 acc[4][2][2];                  // [fm][fn][expert]
        #pragma unroll
        for (int i = 0; i < 4; ++i)
            #pragma unroll
            for (int j = 0; j < 2; ++j)
                #pragma unroll
                for (int e = 0; e < 2; ++e) acc[i][j][e] = vzero;

        const unsigned short* gB0 = gBb + (size_t)(2 * eg)     * C_DIM * D_DIM;
        const unsigned short* gB1 = gBb + (size_t)(2 * eg + 1) * C_DIM * D_DIM;

        for (int kt = 0; kt < D_DIM / 32; ++kt) {
            const int ko = kt * 32;
            async16(gA + ko,               ldsA);          // A rows 0-63
            async16(gA + ko + 64 * D_DIM,  ldsA + 4096);   // A rows 64-127
            async16(gB0 + ko,              ldsB);          // B expert 0
            async16(gB1 + ko,              ldsB + 4096);   // B expert 1

            __syncthreads();

            bf16x8 af[4], bfr[2][2];
            #pragma unroll
            for (int fm = 0; fm < 4; ++fm)
                af[fm] = *(const bf16x8*)(As + (wm * 64 + fm * 16 + ln) * 32 + fq);
            #pragma unroll
            for (int fn = 0; fn < 2; ++fn)
                #pragma unroll
                for (int e = 0; e < 2; ++e)
                    bfr[fn][e] = *(const bf16x8*)(Bs + e * 2048 +
                                    (wn * 32 + fn * 16 + ln) * 32 + fq);
            #pragma unroll
            for (int fm = 0; fm < 4; ++fm)
                #pragma unroll
                for (int fn = 0; fn < 2; ++fn)
                    #pragma unroll
                    for (int e = 0; e < 2; ++e)
                        acc[fm][fn][e] = __builtin_amdgcn_mfma_f32_16x16x32_bf16(
                            af[fm], bfr[fn][e], acc[fm][fn][e], 0, 0, 0);

            __syncthreads();
        }

        // epilogue: comb += gate * exp(acc + bias)   (C/D: col=ln, row=q*4+r)
        #pragma unroll
        for (int e = 0; e < 2; ++e) {
            int eG = eg * 2 + e;
            #pragma unroll
            for (int fn = 0; fn < 2; ++fn) {
                float bval = bs[eG * 64 + wn * 32 + fn * 16 + ln];
                #pragma unroll
                for (int fm = 0; fm < 4; ++fm)
                    #pragma unroll
                    for (int r = 0; r < 4; ++r) {
                        float g = gs[(wm * 64 + fm * 16 + q * 4 + r) * 9 + eG];
                        comb[fm][fn][r] += g * __expf(acc[fm][fn][e][r] + bval);
                    }
            }
        }
    }

    #pragma unroll
    for (int fm = 0; fm < 4; ++fm)
        #pragma unroll
        for (int fn = 0; fn < 2; ++fn)
            #pragma unroll
            for (int r = 0; r < 4; ++r) {
                int row = row0 + wm * 64 + fm * 16 + q * 4 + r;
                int col = col0 + wn * 32 + fn * 16 + ln;
                float c = comb[fm][fn][r];
                c = (c == 0.0f) ? EPS_COMBINE : c;
                out[(size_t)row * C_DIM + col] = __logf(c);
            }
}

extern "C" void kernel_launch(void* const* d_in, const int* in_sizes, int n_in,
                              void* d_out, int out_size, void* d_ws, size_t ws_size,
                              hipStream_t stream) {
    const float* x    = (const float*)d_in[0];
    const float* wg   = (const float*)d_in[1];
    const float* wexp = (const float*)d_in[2];
    const float* bexp = (const float*)d_in[3];
    // d_in[4] is k==4 (hard-coded in kernels)
    float* out = (float*)d_out;
    char*  ws  = (char*)d_ws;

    unsigned short* wT    = (unsigned short*)ws;               // 67108864 B
    unsigned short* xb    = (unsigned short*)(ws + 67108864);  // 8388608 B
    float*          gates = (float*)(ws + 75497472);           // 131072 B

    prep_kernel<<<TP_BLOCKS + B_ROWS / 4, 256, 0, stream>>>(
        x, wg, wexp, xb, wT, gates);

    // moe in 3 COLUMN slices (22/21/21 of 64 col-panels): wT partitioned
    // (no refetch, unlike r8's row-split); drops top-5 threshold to ~118us
    // so prep can surface.
    moe_main_kernel<<<dim3(32, 22), 256, 0, stream>>>(xb, wT, bexp, gates, out, 0);
    moe_main_kernel<<<dim3(32, 21), 256, 0, stream>>>(xb, wT, bexp, gates, out, 22);
    moe_main_kernel<<<dim3(32, 21), 256, 0, stream>>>(xb, wT, bexp, gates, out, 43);

    loss_kernel<<<1, 256, 0, stream>>>(gates, out + (size_t)B_ROWS * C_DIM);
}